// Round 4
// baseline (20633.083 us; speedup 1.0000x reference)
//
#include <hip/hip_runtime.h>
#include <cstdint>
#include <cstddef>

#define MM 4096
#define NSTEP 50
#define DD 100
#define HID 512
#define K0P 128
#define SIGC 0.4f
#define RC 0.05f
#define BMR 16
#define NWG (MM / BMR)   // 256

typedef __bf16 bf16x8 __attribute__((ext_vector_type(8)));
typedef float  f32x4  __attribute__((ext_vector_type(4)));

union Pack4 { __bf16 h[4]; uint2 u2; };

// ---------- weight prep ----------
__global__ void k_transpose(const float* __restrict__ in, __bf16* __restrict__ out,
                            int Ksrc, int Kpad, int N) {
    int idx = blockIdx.x * 256 + threadIdx.x;
    if (idx >= N * Kpad) return;
    int n = idx / Kpad, k = idx - n * Kpad;
    out[idx] = (k < Ksrc) ? (__bf16)in[k * N + n] : (__bf16)0.f;
}

__global__ void k_cast(const float* __restrict__ in, __bf16* __restrict__ out,
                       int Rsrc, int Rpad, int C) {
    int idx = blockIdx.x * 256 + threadIdx.x;
    if (idx >= Rpad * C) return;
    int r = idx / C;
    out[idx] = (r < Rsrc) ? (__bf16)in[idx] : (__bf16)0.f;
}

// ---------- tX writer: swizzled bf16 [16][128], row stride 256B ----------
// 16 threads per row (dg=0..15), 7 cols each starting at 1+d0.
__device__ __forceinline__ void write_tX(char* T, int m, int dg, int d0,
                                         const float* x, float tval) {
    #pragma unroll
    for (int i = 0; i < 7; i++) {
        int col = 1 + d0 + i;
        int po = m * 256 + (((col >> 3) ^ (m & 7)) << 4) + (col & 7) * 2;
        *(__bf16*)(T + po) = (__bf16)x[i];
    }
    if (dg == 0) {
        int po = m * 256 + ((m & 7) << 4);
        *(__bf16*)(T + po) = (__bf16)tval;
    }
    if (dg == 15) {
        #pragma unroll
        for (int c = 113; c < 128; c++) {
            int po = m * 256 + (((c >> 3) ^ (m & 7)) << 4) + (c & 7) * 2;
            *(__bf16*)(T + po) = (__bf16)0.f;
        }
    }
}

// ---------- one GEMM phase: C[m][n] = sum_k A[m][k] * B[n][k] ----------
// A: LDS swizzled [16][K] bf16; B: global (L2/L3-resident weights).
// 4 waves, wave tile 16 rows x (NJ*16) cols. In-place epilogue (post-MFMA barrier).
// EPI 0: fwd:      v+=bias; sin->sOut, cos->sStash
// EPI 1: fwd L3:   v+=bias; cos*W4->sOut; u partials -> u_lds
// EPI 2: bwd:      v*=sStash -> sOut
// EPI 3: bwd L0:   v (f32) -> sOut as Z [16][132] f32
template <int NK, int NJ, int EPI>
__device__ __forceinline__ void phase(
    int tid, const char* __restrict__ sA, int aRS,
    const __bf16* __restrict__ Bw, int K,
    const float* __restrict__ bias, const float* __restrict__ W4,
    char* __restrict__ sOut, char* __restrict__ sStash,
    float* __restrict__ u_lds) {

    const int lane = tid & 63;
    const int wave = tid >> 6;
    const int lr = lane & 15, lg = lane >> 4;
    const int wc = wave * (NJ * 16);

    f32x4 acc[NJ] = {};
    bf16x8 aB[3];
    bf16x8 bB[3][NJ];

    const __bf16* bp = Bw + (size_t)(wc + lr) * K + lg * 8;

    #define LOADA(slot, ks)                                                       \
        {   int ch = (ks) * 4 + lg;                                               \
            aB[slot] = *(const bf16x8*)(sA + lr * aRS + ((ch ^ (lr & 7)) << 4)); }
    #define LOADB(slot, ks)                                                       \
        {   _Pragma("unroll")                                                     \
            for (int nj = 0; nj < NJ; nj++)                                       \
                bB[slot][nj] = *(const bf16x8*)(bp + (size_t)nj * 16 * K + (ks) * 32); }

    LOADA(0, 0) LOADB(0, 0)
    LOADA(1, 1) LOADB(1, 1)
    #pragma unroll
    for (int ks = 0; ks < NK; ks++) {
        if (ks + 2 < NK) { LOADA((ks + 2) % 3, ks + 2) LOADB((ks + 2) % 3, ks + 2) }
        __builtin_amdgcn_s_setprio(1);
        #pragma unroll
        for (int nj = 0; nj < NJ; nj++)
            acc[nj] = __builtin_amdgcn_mfma_f32_16x16x32_bf16(
                bB[ks % 3][nj], aB[ks % 3], acc[nj], 0, 0, 0);
        __builtin_amdgcn_s_setprio(0);
    }
    #undef LOADA
    #undef LOADB

    __syncthreads();   // all waves done reading sA -> in-place writes now safe
    if (EPI == 1) {
        if (tid < BMR) u_lds[tid] = 0.f;
        __syncthreads();
    }

    const int m = lr;
    float up = 0.f;
    #pragma unroll
    for (int nj = 0; nj < NJ; nj++) {
        const int n = wc + nj * 16 + lg * 4;
        f32x4 v = acc[nj];
        if (EPI == 3) {
            *(f32x4*)(sOut + (size_t)(m * 132 + n) * 4) = v;
        } else {
            const int po = m * 1024 + ((((n >> 3) ^ (m & 7))) << 4) + (n & 7) * 2;
            if (EPI == 0) {
                f32x4 bv = *(const f32x4*)(bias + n);
                Pack4 ps, pc;
                #pragma unroll
                for (int r = 0; r < 4; r++) {
                    float s, c;
                    __sincosf(v[r] + bv[r], &s, &c);
                    ps.h[r] = (__bf16)s;
                    pc.h[r] = (__bf16)c;
                }
                *(uint2*)(sOut + po) = ps.u2;
                *(uint2*)(sStash + po) = pc.u2;
            } else if (EPI == 1) {
                f32x4 bv = *(const f32x4*)(bias + n);
                f32x4 wv = *(const f32x4*)(W4 + n);
                Pack4 pg;
                #pragma unroll
                for (int r = 0; r < 4; r++) {
                    float s, c;
                    __sincosf(v[r] + bv[r], &s, &c);
                    up += s * wv[r];
                    pg.h[r] = (__bf16)(c * wv[r]);
                }
                *(uint2*)(sOut + po) = pg.u2;
            } else {  // EPI == 2
                Pack4 pm = *(const Pack4*)(sStash + po);
                Pack4 pg;
                #pragma unroll
                for (int r = 0; r < 4; r++)
                    pg.h[r] = (__bf16)(v[r] * (float)pm.h[r]);
                *(uint2*)(sOut + po) = pg.u2;
            }
        }
    }
    if (EPI == 1) {
        up += __shfl_xor(up, 16);
        up += __shfl_xor(up, 32);
        if (lg == 0) atomicAdd(&u_lds[lr], up);
    }
}

// ---------- the megakernel ----------
__global__ __launch_bounds__(256, 2) void mega(
    const float* __restrict__ t, const float* __restrict__ W,
    const float* __restrict__ Xi,
    const __bf16* __restrict__ wt0, const __bf16* __restrict__ wt1,
    const __bf16* __restrict__ wt2, const __bf16* __restrict__ wt3,
    const __bf16* __restrict__ wd0, const __bf16* __restrict__ wd1,
    const __bf16* __restrict__ wd2, const __bf16* __restrict__ wd3,
    const float* __restrict__ b0, const float* __restrict__ b1,
    const float* __restrict__ b2, const float* __restrict__ b3,
    const float* __restrict__ W4, const float* __restrict__ b4,
    float* __restrict__ acc) {

    extern __shared__ char lds[];
    char* A0 = lds;                 // 16KB act slot (in-place); Z f32 [16][132] at 0; tX at +8448
    char* S1 = lds + 16384;         // cos(z0)
    char* S2 = lds + 32768;         // cos(z1)
    char* S3 = lds + 49152;         // cos(z2)
    float* u_lds = (float*)(lds + 65536);   // 64 floats scratch

    const int tid = threadIdx.x;
    const int wgrow = blockIdx.x * BMR;
    const int em = tid >> 4, edg = tid & 15, ed0 = edg * 7;
    const int grow = wgrow + em;
    char* tX = A0 + 8448;

    float x[7];
    #pragma unroll
    for (int i = 0; i < 7; i++) {
        int d = ed0 + i;
        x[i] = (d < DD) ? Xi[d] : 0.f;
    }
    float ytil = 0.f, resid = 0.f, u_reg = 0.f;
    const float b4v = b4[0];

    write_tX(tX, em, edg, ed0, x, t[grow * (NSTEP + 1)]);
    __syncthreads();

    for (int n = 0; n <= NSTEP; n++) {
        // forward
        phase<4, 8, 0>(tid, tX, 256, wt0, K0P, b0, nullptr, A0, S1, nullptr);
        __syncthreads();
        phase<16, 8, 0>(tid, A0, 1024, wt1, HID, b1, nullptr, A0, S2, nullptr);
        __syncthreads();
        phase<16, 8, 0>(tid, A0, 1024, wt2, HID, b2, nullptr, A0, S3, nullptr);
        __syncthreads();
        phase<16, 8, 1>(tid, A0, 1024, wt3, HID, b3, W4, A0, nullptr, u_lds);
        __syncthreads();
        u_reg = u_lds[em] + b4v;
        // backward (u_lds region untouched by phases below)
        phase<16, 8, 2>(tid, A0, 1024, wd3, HID, nullptr, nullptr, A0, S3, nullptr);
        __syncthreads();
        phase<16, 8, 2>(tid, A0, 1024, wd2, HID, nullptr, nullptr, A0, S2, nullptr);
        __syncthreads();
        phase<16, 8, 2>(tid, A0, 1024, wd1, HID, nullptr, nullptr, A0, S1, nullptr);
        __syncthreads();
        phase<16, 2, 3>(tid, A0, 1024, wd0, HID, nullptr, nullptr, A0, nullptr, nullptr);
        __syncthreads();

        // Euler / terminal: Z f32 [16][132] at A0
        const float* Zs = (const float*)A0 + em * 132;
        if (n < NSTEP) {
            float t0v = t[grow * (NSTEP + 1) + n];
            float t1v = t[grow * (NSTEP + 1) + n + 1];
            const float* Wr0 = W + ((size_t)grow * (NSTEP + 1) + n) * DD;
            const float* Wr1 = Wr0 + DD;
            float pXZ = 0.f, pZs = 0.f;
            #pragma unroll
            for (int i = 0; i < 7; i++) {
                int d = ed0 + i;
                if (d < DD) {
                    float z = Zs[1 + d];
                    float dWv = Wr1[d] - Wr0[d];
                    float s = SIGC * x[i] * dWv;
                    pXZ += x[i] * z;
                    pZs += z * s;
                    x[i] += s;
                }
            }
            pXZ += __shfl_xor(pXZ, 1); pXZ += __shfl_xor(pXZ, 2);
            pXZ += __shfl_xor(pXZ, 4); pXZ += __shfl_xor(pXZ, 8);
            pZs += __shfl_xor(pZs, 1); pZs += __shfl_xor(pZs, 2);
            pZs += __shfl_xor(pZs, 4); pZs += __shfl_xor(pZs, 8);
            if (edg == 0) {
                if (n >= 1) { float dd = u_reg - ytil; resid += dd * dd; }
                float phi = RC * (u_reg - pXZ);
                ytil = u_reg + phi * (t1v - t0v) + pZs;
            }
            write_tX(tX, em, edg, ed0, x, t1v);
        } else {
            float gX = 0.f, sD = 0.f;
            #pragma unroll
            for (int i = 0; i < 7; i++) {
                int d = ed0 + i;
                if (d < DD) {
                    float z = Zs[1 + d];
                    gX += x[i] * x[i];
                    float e = z - 2.f * x[i];
                    sD += e * e;
                }
            }
            gX += __shfl_xor(gX, 1); gX += __shfl_xor(gX, 2);
            gX += __shfl_xor(gX, 4); gX += __shfl_xor(gX, 8);
            sD += __shfl_xor(sD, 1); sD += __shfl_xor(sD, 2);
            sD += __shfl_xor(sD, 4); sD += __shfl_xor(sD, 8);
            if (edg == 0) {
                float e = u_reg - gX;
                resid += e * e + sD;
            }
        }
        __syncthreads();
    }

    // block reduction of resid -> one atomic per WG
    float r = resid;
    #pragma unroll
    for (int off = 1; off < 64; off <<= 1) r += __shfl_xor(r, off);
    if ((tid & 63) == 0) u_lds[32 + (tid >> 6)] = r;
    __syncthreads();
    if (tid == 0)
        atomicAdd(acc, u_lds[32] + u_lds[33] + u_lds[34] + u_lds[35]);
}

__global__ void k_final(const float* __restrict__ acc, float* __restrict__ out) {
    out[0] = acc[0] / (float)MM;
}

// ---------- host ----------
extern "C" void kernel_launch(void* const* d_in, const int* in_sizes, int n_in,
                              void* d_out, int out_size, void* d_ws, size_t ws_size,
                              hipStream_t stream) {
    (void)in_sizes; (void)n_in; (void)out_size; (void)ws_size;
    const float* t  = (const float*)d_in[0];
    const float* W  = (const float*)d_in[1];
    const float* Xi = (const float*)d_in[2];
    const float* Wm[5];
    const float* bb[5];
    for (int i = 0; i < 5; i++) {
        Wm[i] = (const float*)d_in[3 + 2 * i];
        bb[i] = (const float*)d_in[4 + 2 * i];
    }

    char* p = (char*)d_ws;
    auto alloc = [&](size_t bytes) -> void* {
        void* r = (void*)p;
        p += (bytes + 255) & ~(size_t)255;
        return r;
    };

    __bf16* wt[4];
    wt[0] = (__bf16*)alloc((size_t)HID * K0P * 2);
    for (int i = 1; i < 4; i++) wt[i] = (__bf16*)alloc((size_t)HID * HID * 2);
    __bf16* wd[4];
    wd[0] = (__bf16*)alloc((size_t)K0P * HID * 2);
    for (int i = 1; i < 4; i++) wd[i] = (__bf16*)alloc((size_t)HID * HID * 2);
    float* acc = (float*)alloc(256);

    hipMemsetAsync(acc, 0, 256, stream);

    k_transpose<<<(HID * K0P + 255) / 256, 256, 0, stream>>>(Wm[0], wt[0], 101, K0P, HID);
    for (int i = 1; i < 4; i++)
        k_transpose<<<(HID * HID + 255) / 256, 256, 0, stream>>>(Wm[i], wt[i], HID, HID, HID);
    k_cast<<<(K0P * HID + 255) / 256, 256, 0, stream>>>(Wm[0], wd[0], 101, K0P, HID);
    for (int i = 1; i < 4; i++)
        k_cast<<<(HID * HID + 255) / 256, 256, 0, stream>>>(Wm[i], wd[i], HID, HID, HID);

    hipFuncSetAttribute((const void*)mega,
                        hipFuncAttributeMaxDynamicSharedMemorySize, 65792);

    mega<<<dim3(NWG), dim3(256), 65792, stream>>>(
        t, W, Xi,
        wt[0], wt[1], wt[2], wt[3],
        wd[0], wd[1], wd[2], wd[3],
        bb[0], bb[1], bb[2], bb[3],
        Wm[4], bb[4], acc);

    k_final<<<1, 1, 0, stream>>>(acc, (float*)d_out);
}

// Round 6
// 4859.992 us; speedup vs baseline: 4.2455x; 4.2455x over previous
//
#include <hip/hip_runtime.h>
#include <cstdint>
#include <cstddef>

// ---------- constants ----------
#define MM 4096
#define NSTEP 50
#define DD 100
#define HID 512
#define K0P 128          // 101 padded to 128
#define SIGC 0.4f
#define RC 0.05f

typedef __bf16 bf16x8 __attribute__((ext_vector_type(8)));
typedef float  f32x4  __attribute__((ext_vector_type(4)));

typedef const __attribute__((address_space(1))) void* gvp;
typedef __attribute__((address_space(3))) void* lvp;

static __device__ __forceinline__ void load_lds16(const void* g, void* l) {
    __builtin_amdgcn_global_load_lds((gvp)g, (lvp)l, 16, 0, 0);
}

// ---------- weight prep ----------
__global__ void k_transpose(const float* __restrict__ in, __bf16* __restrict__ out,
                            int Ksrc, int Kpad, int N) {
    int idx = blockIdx.x * 256 + threadIdx.x;
    if (idx >= N * Kpad) return;
    int n = idx / Kpad, k = idx - n * Kpad;
    out[idx] = (k < Ksrc) ? (__bf16)in[k * N + n] : (__bf16)0.f;
}

__global__ void k_cast(const float* __restrict__ in, __bf16* __restrict__ out,
                       int Rsrc, int Rpad, int C) {
    int idx = blockIdx.x * 256 + threadIdx.x;
    if (idx >= Rpad * C) return;
    int r = idx / C;
    out[idx] = (r < Rsrc) ? (__bf16)in[idx] : (__bf16)0.f;
}

// ---------- init: X0 = tile(Xi), tX row [t0, X0, 0-pad], Y = b4 ----------
__global__ __launch_bounds__(256) void k_init(const float* __restrict__ t,
                                              const float* __restrict__ Xi,
                                              const float* __restrict__ b4,
                                              float* __restrict__ X0,
                                              float* __restrict__ Y,
                                              __bf16* __restrict__ tX) {
    int m = blockIdx.x * 4 + (threadIdx.x >> 6);
    int lane = threadIdx.x & 63;
    for (int ii = 0; ii < 2; ii++) {
        int d = lane + ii * 64;
        if (d < DD) {
            float x = Xi[d];
            X0[m * DD + d] = x;
            tX[(size_t)m * K0P + 1 + d] = (__bf16)x;
        } else if (d < K0P - 1) {
            tX[(size_t)m * K0P + 1 + d] = (__bf16)0.f;
        }
    }
    if (lane == 0) {
        tX[(size_t)m * K0P] = (__bf16)t[m * (NSTEP + 1)];
        Y[m] = b4[0];
    }
}

// ---------- unified GEMM: C[m][n] = sum_k A[m][k]*Bm[n][k] ----------
// BM=64, BN=128, BK=64, 256 threads, 4 waves (2x2), wave tile 32x64.
// Double-buffered LDS (T3-minimum): stage(k+1) -> compute(k) -> one barrier.
// LDS XOR-swizzle via pre-swizzled global source (round-1-verified indexing).
// EPI 0: fwd layer: v+=bias; sin->out0, cos->out1
// EPI 1: bwd layer: v*=cmul; ->out0
// EPI 2: fwd L3: v+=bias; cos*W4->out0; Y[m] += sin*W4 (atomic)
// EPI 3: bwd L0 + Euler/terminal fused
template <int EPI>
__global__ __launch_bounds__(256, 2) void k_gemm(
    const __bf16* __restrict__ A, const __bf16* __restrict__ Bm,
    const float* __restrict__ bias, const __bf16* __restrict__ cmul,
    __bf16* __restrict__ out0, __bf16* __restrict__ out1,
    const float* __restrict__ W4, float* __restrict__ Y,
    const float* __restrict__ t, const float* __restrict__ Wb,
    float* __restrict__ X, float* __restrict__ Ytil,
    __bf16* __restrict__ tXout, const float* __restrict__ b4,
    float* __restrict__ acc, int n, int K, int Nout) {

    __shared__ __align__(16) char lds[49152];
    // buf0: A at 0, B at 16384; buf1: A at 8192, B at 32768

    const int tid = threadIdx.x;
    const int wave = tid >> 6, lane = tid & 63;
    const int lr = lane & 15, lg = lane >> 4;
    const int rowBlk = blockIdx.y * 64;
    const int colBlk = blockIdx.x * 128;
    const int wr = (wave >> 1) * 32;   // wave row base in tile
    const int wc = (wave & 1) * 64;    // wave col base in tile

    f32x4 acc4[2][4] = {};

    // staging precompute (A: 2 issues, B: 4 issues of 16B/thread) — round-1-verified
    int aRow[2], aG[2], bRow[4], bG[4];
    #pragma unroll
    for (int it = 0; it < 2; it++) {
        int chunk = it * 256 + tid;
        aRow[it] = chunk >> 3;
        aG[it] = (chunk & 7) ^ (aRow[it] & 7);
    }
    #pragma unroll
    for (int it = 0; it < 4; it++) {
        int chunk = it * 256 + tid;
        bRow[it] = chunk >> 3;
        bG[it] = (chunk & 7) ^ (bRow[it] & 7);
    }

    const int NK = K >> 6;

    // stage(kb, buf)
    #define STAGE(kb, buf)                                                         \
        {   char* Ad_ = lds + (buf) * 8192 + wave * 1024;                          \
            char* Bd_ = lds + 16384 + (buf) * 16384 + wave * 1024;                 \
            int k0_ = (kb) << 6;                                                   \
            _Pragma("unroll")                                                      \
            for (int it = 0; it < 2; it++)                                         \
                load_lds16(A + (size_t)(rowBlk + aRow[it]) * K + k0_ + aG[it] * 8, \
                           Ad_ + it * 4096);                                       \
            _Pragma("unroll")                                                      \
            for (int it = 0; it < 4; it++)                                         \
                load_lds16(Bm + (size_t)(colBlk + bRow[it]) * K + k0_ + bG[it] * 8,\
                           Bd_ + it * 4096); }

    STAGE(0, 0)
    __syncthreads();

    for (int kb = 0; kb < NK; kb++) {
        const int cur = kb & 1;
        if (kb + 1 < NK) STAGE(kb + 1, cur ^ 1)
        const char* As = lds + cur * 8192;
        const char* Bs = lds + 16384 + cur * 16384;
        #pragma unroll
        for (int ks = 0; ks < 2; ks++) {
            bf16x8 aF[2], bF[4];
            #pragma unroll
            for (int mi = 0; mi < 2; mi++) {
                int row = wr + mi * 16 + lr;
                int p = (ks * 4 + lg) ^ (row & 7);
                aF[mi] = *(const bf16x8*)(As + row * 128 + p * 16);
            }
            #pragma unroll
            for (int nj = 0; nj < 4; nj++) {
                int row = wc + nj * 16 + lr;
                int p = (ks * 4 + lg) ^ (row & 7);
                bF[nj] = *(const bf16x8*)(Bs + row * 128 + p * 16);
            }
            #pragma unroll
            for (int mi = 0; mi < 2; mi++)
                #pragma unroll
                for (int nj = 0; nj < 4; nj++)
                    acc4[mi][nj] = __builtin_amdgcn_mfma_f32_16x16x32_bf16(
                        aF[mi], bF[nj], acc4[mi][nj], 0, 0, 0);
        }
        __syncthreads();   // stage(kb+1) landed; all reads of buf cur done
    }
    #undef STAGE

    if (EPI == 0) {
        #pragma unroll
        for (int nj = 0; nj < 4; nj++) {
            int col = colBlk + wc + nj * 16 + lr;
            float bv = bias[col];
            #pragma unroll
            for (int mi = 0; mi < 2; mi++)
                #pragma unroll
                for (int r = 0; r < 4; r++) {
                    int row = rowBlk + wr + mi * 16 + lg * 4 + r;
                    float v = acc4[mi][nj][r] + bv;
                    float s, c;
                    __sincosf(v, &s, &c);
                    out0[(size_t)row * Nout + col] = (__bf16)s;
                    out1[(size_t)row * Nout + col] = (__bf16)c;
                }
        }
    } else if (EPI == 1) {
        #pragma unroll
        for (int nj = 0; nj < 4; nj++) {
            int col = colBlk + wc + nj * 16 + lr;
            #pragma unroll
            for (int mi = 0; mi < 2; mi++)
                #pragma unroll
                for (int r = 0; r < 4; r++) {
                    int row = rowBlk + wr + mi * 16 + lg * 4 + r;
                    float v = acc4[mi][nj][r] * (float)cmul[(size_t)row * Nout + col];
                    out0[(size_t)row * Nout + col] = (__bf16)v;
                }
        }
    } else if (EPI == 2) {
        float ysum[2][4] = {};
        #pragma unroll
        for (int nj = 0; nj < 4; nj++) {
            int col = colBlk + wc + nj * 16 + lr;
            float bv = bias[col];
            float w4 = W4[col];
            #pragma unroll
            for (int mi = 0; mi < 2; mi++)
                #pragma unroll
                for (int r = 0; r < 4; r++) {
                    int row = rowBlk + wr + mi * 16 + lg * 4 + r;
                    float v = acc4[mi][nj][r] + bv;
                    float s, c;
                    __sincosf(v, &s, &c);
                    out0[(size_t)row * Nout + col] = (__bf16)(c * w4);
                    ysum[mi][r] += s * w4;
                }
        }
        #pragma unroll
        for (int mi = 0; mi < 2; mi++)
            #pragma unroll
            for (int r = 0; r < 4; r++) {
                float v = ysum[mi][r];
                v += __shfl_xor(v, 1);
                v += __shfl_xor(v, 2);
                v += __shfl_xor(v, 4);
                v += __shfl_xor(v, 8);
                if (lr == 0) {
                    int row = rowBlk + wr + mi * 16 + lg * 4 + r;
                    atomicAdd(&Y[row], v);
                }
            }
    } else {  // EPI == 3: stash Z in LDS, fused Euler / terminal
        __syncthreads();
        float* Zs = (float*)lds;   // [64][132] f32 = 33792 B
        #pragma unroll
        for (int nj = 0; nj < 4; nj++) {
            int col = wc + nj * 16 + lr;
            #pragma unroll
            for (int mi = 0; mi < 2; mi++)
                #pragma unroll
                for (int r = 0; r < 4; r++) {
                    int rl = wr + mi * 16 + lg * 4 + r;
                    Zs[rl * 132 + col] = acc4[mi][nj][r];
                }
        }
        __syncthreads();
        float resid = 0.f;
        for (int rl = 0; rl < 16; rl++) {
            int lrow = wave * 16 + rl;
            int grow = rowBlk + lrow;
            float t0v = 0.f, t1v = 0.f;
            if (n < NSTEP) {
                t0v = t[grow * (NSTEP + 1) + n];
                t1v = t[grow * (NSTEP + 1) + n + 1];
            }
            float pXZ = 0.f, pZs = 0.f, gX = 0.f, sD = 0.f;
            #pragma unroll
            for (int ii = 0; ii < 2; ii++) {
                int d = lane + ii * 64;
                if (d < DD) {
                    float x0 = X[grow * DD + d];
                    float z = Zs[lrow * 132 + 1 + d];
                    if (n < NSTEP) {
                        float dWv = Wb[((size_t)grow * (NSTEP + 1) + n + 1) * DD + d] -
                                    Wb[((size_t)grow * (NSTEP + 1) + n) * DD + d];
                        float s = SIGC * x0 * dWv;
                        pXZ += x0 * z;
                        pZs += z * s;
                        float x1 = x0 + s;
                        X[grow * DD + d] = x1;
                        tXout[(size_t)grow * K0P + 1 + d] = (__bf16)x1;
                    } else {
                        gX += x0 * x0;
                        float e = z - 2.f * x0;
                        sD += e * e;
                    }
                }
            }
            for (int off = 32; off; off >>= 1) {
                pXZ += __shfl_down(pXZ, off);
                pZs += __shfl_down(pZs, off);
                gX  += __shfl_down(gX, off);
                sD  += __shfl_down(sD, off);
            }
            if (lane == 0) {
                float y0 = Y[grow];
                if (n >= 1) {
                    float dd = y0 - Ytil[grow];
                    resid += dd * dd;
                }
                if (n < NSTEP) {
                    float phi = RC * (y0 - pXZ);
                    Ytil[grow] = y0 + phi * (t1v - t0v) + pZs;
                    tXout[(size_t)grow * K0P] = (__bf16)t1v;
                    Y[grow] = b4[0];   // init accumulator for next step's fwd L3
                } else {
                    float e = y0 - gX;
                    resid += e * e + sD;
                }
            }
        }
        if (lane == 0) atomicAdd(acc, resid);
    }
}

__global__ void k_final(const float* __restrict__ acc, float* __restrict__ out) {
    out[0] = acc[0] / (float)MM;
}

// ---------- host ----------
extern "C" void kernel_launch(void* const* d_in, const int* in_sizes, int n_in,
                              void* d_out, int out_size, void* d_ws, size_t ws_size,
                              hipStream_t stream) {
    (void)in_sizes; (void)n_in; (void)out_size; (void)ws_size;
    const float* t  = (const float*)d_in[0];
    const float* W  = (const float*)d_in[1];
    const float* Xi = (const float*)d_in[2];
    const float* Wm[5];
    const float* bb[5];
    for (int i = 0; i < 5; i++) {
        Wm[i] = (const float*)d_in[3 + 2 * i];
        bb[i] = (const float*)d_in[4 + 2 * i];
    }

    char* p = (char*)d_ws;
    auto alloc = [&](size_t bytes) -> void* {
        void* r = (void*)p;
        p += (bytes + 255) & ~(size_t)255;
        return r;
    };

    __bf16* wt[4];
    wt[0] = (__bf16*)alloc((size_t)HID * K0P * 2);
    for (int i = 1; i < 4; i++) wt[i] = (__bf16*)alloc((size_t)HID * HID * 2);
    __bf16* wd[4];
    wd[0] = (__bf16*)alloc((size_t)K0P * HID * 2);
    for (int i = 1; i < 4; i++) wd[i] = (__bf16*)alloc((size_t)HID * HID * 2);
    __bf16* tX = (__bf16*)alloc((size_t)MM * K0P * 2);
    __bf16 *a[3], *c[3];
    for (int i = 0; i < 3; i++) a[i] = (__bf16*)alloc((size_t)MM * HID * 2);
    for (int i = 0; i < 3; i++) c[i] = (__bf16*)alloc((size_t)MM * HID * 2);
    __bf16* gza = (__bf16*)alloc((size_t)MM * HID * 2);
    __bf16* gzb = (__bf16*)alloc((size_t)MM * HID * 2);
    float* X    = (float*)alloc((size_t)MM * DD * 4);
    float* Y    = (float*)alloc((size_t)MM * 4);
    float* Ytil = (float*)alloc((size_t)MM * 4);
    float* acc  = (float*)alloc(256);

    hipMemsetAsync(acc, 0, 256, stream);

    // weight prep
    k_transpose<<<(HID * K0P + 255) / 256, 256, 0, stream>>>(Wm[0], wt[0], 101, K0P, HID);
    for (int i = 1; i < 4; i++)
        k_transpose<<<(HID * HID + 255) / 256, 256, 0, stream>>>(Wm[i], wt[i], HID, HID, HID);
    k_cast<<<(K0P * HID + 255) / 256, 256, 0, stream>>>(Wm[0], wd[0], 101, K0P, HID);
    for (int i = 1; i < 4; i++)
        k_cast<<<(HID * HID + 255) / 256, 256, 0, stream>>>(Wm[i], wd[i], HID, HID, HID);

    k_init<<<MM / 4, 256, 0, stream>>>(t, Xi, bb[4], X, Y, tX);

    dim3 gBig(HID / 128, MM / 64);   // (4, 64)
    dim3 gZ(1, MM / 64);             // (1, 64)

    for (int n = 0; n <= NSTEP; n++) {
        // forward
        k_gemm<0><<<gBig, 256, 0, stream>>>(tX, wt[0], bb[0], nullptr, a[0], c[0],
            nullptr, nullptr, nullptr, nullptr, nullptr, nullptr, nullptr, nullptr,
            nullptr, n, K0P, HID);
        k_gemm<0><<<gBig, 256, 0, stream>>>(a[0], wt[1], bb[1], nullptr, a[1], c[1],
            nullptr, nullptr, nullptr, nullptr, nullptr, nullptr, nullptr, nullptr,
            nullptr, n, HID, HID);
        k_gemm<0><<<gBig, 256, 0, stream>>>(a[1], wt[2], bb[2], nullptr, a[2], c[2],
            nullptr, nullptr, nullptr, nullptr, nullptr, nullptr, nullptr, nullptr,
            nullptr, n, HID, HID);
        k_gemm<2><<<gBig, 256, 0, stream>>>(a[2], wt[3], bb[3], nullptr, gza, nullptr,
            Wm[4], Y, nullptr, nullptr, nullptr, nullptr, nullptr, nullptr,
            nullptr, n, HID, HID);
        // backward
        k_gemm<1><<<gBig, 256, 0, stream>>>(gza, wd[3], nullptr, c[2], gzb, nullptr,
            nullptr, nullptr, nullptr, nullptr, nullptr, nullptr, nullptr, nullptr,
            nullptr, n, HID, HID);
        k_gemm<1><<<gBig, 256, 0, stream>>>(gzb, wd[2], nullptr, c[1], gza, nullptr,
            nullptr, nullptr, nullptr, nullptr, nullptr, nullptr, nullptr, nullptr,
            nullptr, n, HID, HID);
        k_gemm<1><<<gBig, 256, 0, stream>>>(gza, wd[1], nullptr, c[0], gzb, nullptr,
            nullptr, nullptr, nullptr, nullptr, nullptr, nullptr, nullptr, nullptr,
            nullptr, n, HID, HID);
        // bwd L0 + Euler(n+1) / terminal
        k_gemm<3><<<gZ, 256, 0, stream>>>(gzb, wd[0], nullptr, nullptr, nullptr, nullptr,
            nullptr, Y, t, W, X, Ytil, tX, bb[4], acc, n, HID, K0P);
    }
    k_final<<<1, 1, 0, stream>>>(acc, (float*)d_out);
}